// Round 1
// baseline (166.824 us; speedup 1.0000x reference)
//
#include <hip/hip_runtime.h>

#define CC 16
#define BB 16384
#define DD 256
#define BT 32
#define NT 512

typedef float f32x4 __attribute__((ext_vector_type(4)));
typedef short bf16x8 __attribute__((ext_vector_type(8)));

__device__ __forceinline__ unsigned short f2bf(float f) {
    unsigned u = __builtin_bit_cast(unsigned, f);
    u += 0x7fffu + ((u >> 16) & 1u);
    return (unsigned short)(u >> 16);
}

__device__ __forceinline__ bf16x8 pack8(f32x4 a, f32x4 b) {
    bf16x8 v;
    v[0] = (short)f2bf(a[0]); v[1] = (short)f2bf(a[1]);
    v[2] = (short)f2bf(a[2]); v[3] = (short)f2bf(a[3]);
    v[4] = (short)f2bf(b[0]); v[5] = (short)f2bf(b[1]);
    v[6] = (short)f2bf(b[2]); v[7] = (short)f2bf(b[3]);
    return v;
}

__device__ __forceinline__ float sigm(float x) {
    return __builtin_amdgcn_rcpf(1.0f + __expf(-x));
}
__device__ __forceinline__ float tanhf_(float x) {
    return 2.0f * __builtin_amdgcn_rcpf(1.0f + __expf(-2.0f * x)) - 1.0f;
}

// Fused TreeLSTM node update.
// Per block: BT=32 batch rows, all 256 gate cols. 8 waves, 32 cols/wave.
// LDS: double-buffered bf16 h-tile [32][256], XOR-swizzled (byte ^= (row&7)<<4)
// so ds_read_b128 A-fragments are conflict-free (2-way = free).
__global__ __launch_bounds__(NT, 2) void treelstm(
    const float* __restrict__ cmem,   // [C][B][D] children_memory
    const float* __restrict__ chid,   // [C][B][D] children_hidden
    const float* __restrict__ Wf,     // [D][D]
    const float* __restrict__ bfv_g,  // [D]
    const float* __restrict__ Wiou,   // [3D][D]
    const float* __restrict__ biou,   // [3D]
    float* __restrict__ out)          // [2][B][D]: node_memory, node_hidden
{
    __shared__ alignas(16) unsigned char Abuf[2][BT * DD * 2];

    const int tid  = threadIdx.x;
    const int lane = tid & 63;
    const int wid  = tid >> 6;
    const int l15  = lane & 15;
    const int l4   = lane >> 4;    // 0..3
    const int b0   = blockIdx.x * BT;
    const int wc0  = wid * 32;     // this wave's 32 output columns

    // ---- Wf B-fragments held in registers for the whole c-loop.
    // B-frag (16x16x32): lane holds B[k][n] with n = l&15, k = (l>>4)*8 + j.
    // B[d][e] = Wf[e][d]  (einsum cbd,ed->cbe)
    bf16x8 wfr[2][8];
#pragma unroll
    for (int n = 0; n < 2; ++n) {
        const float* wrow = Wf + (size_t)(wc0 + n * 16 + l15) * DD + l4 * 8;
#pragma unroll
        for (int k = 0; k < 8; ++k) {
            f32x4 x0 = *(const f32x4*)(wrow + k * 32);
            f32x4 x1 = *(const f32x4*)(wrow + k * 32 + 4);
            wfr[n][k] = pack8(x0, x1);
        }
    }
    float bfr[2];
#pragma unroll
    for (int n = 0; n < 2; ++n) bfr[n] = bfv_g[wc0 + n * 16 + l15];

    // ---- staging geometry: thread stages 2 groups of 8 floats
    int sgoff[2], sloff[2];
#pragma unroll
    for (int g = 0; g < 2; ++g) {
        int gg = tid + g * NT;        // 0..1023
        int r  = gg >> 5;             // row 0..31
        int d0 = (gg & 31) * 8;       // col 0..248
        sgoff[g] = (b0 + r) * DD + d0;
        sloff[g] = r * 512 + ((d0 * 2) ^ ((r & 7) << 4));
    }

    float hs[2][8];   // hidden_sum accumulator (f32, at staging positions)
#pragma unroll
    for (int g = 0; g < 2; ++g)
#pragma unroll
        for (int j = 0; j < 8; ++j) hs[g][j] = 0.0f;

    // ---- prologue: stage child 0
    {
        f32x4 h0[2][2];
#pragma unroll
        for (int g = 0; g < 2; ++g) {
            const float* p = chid + sgoff[g];
            h0[g][0] = *(const f32x4*)p;
            h0[g][1] = *(const f32x4*)(p + 4);
        }
#pragma unroll
        for (int g = 0; g < 2; ++g) {
#pragma unroll
            for (int j = 0; j < 4; ++j) { hs[g][j] += h0[g][0][j]; hs[g][4 + j] += h0[g][1][j]; }
            *(bf16x8*)&Abuf[0][sloff[g]] = pack8(h0[g][0], h0[g][1]);
        }
    }
    __syncthreads();

    // A-fragment LDS addressing (swizzle-consistent):
    // lane reads row m*16+(l&15), k-bytes (k*64 + l4*16) ^ ((row&7)<<4)
    const int colbase = (l4 * 16) ^ ((l15 & 7) << 4);
    const int rb0 = l15 * 512;
    const int rb1 = (16 + l15) * 512;

    float nmv[2][2][4];   // node_memory accumulator in C-frag layout
#pragma unroll
    for (int m = 0; m < 2; ++m)
#pragma unroll
        for (int n = 0; n < 2; ++n)
#pragma unroll
            for (int j = 0; j < 4; ++j) nmv[m][n][j] = 0.0f;

    // cm element offset within one [B][D] slab, C-frag layout
    const int cmbase = (b0 + l4 * 4) * DD + wc0 + l15;

    for (int c = 0; c < CC; ++c) {
        // prefetch children_memory[c] for this lane's 16 output elems
        const float* cmc = cmem + (size_t)c * (BB * DD);
        float cmv[2][2][4];
#pragma unroll
        for (int m = 0; m < 2; ++m)
#pragma unroll
            for (int n = 0; n < 2; ++n)
#pragma unroll
                for (int j = 0; j < 4; ++j)
                    cmv[m][n][j] = cmc[cmbase + m * (16 * DD) + j * DD + n * 16];

        // prefetch children_hidden[c+1]
        f32x4 hv[2][2];
        const bool more = (c + 1 < CC);
        if (more) {
            const float* hc = chid + (size_t)(c + 1) * (BB * DD);
#pragma unroll
            for (int g = 0; g < 2; ++g) {
                const float* p = hc + sgoff[g];
                hv[g][0] = *(const f32x4*)p;
                hv[g][1] = *(const f32x4*)(p + 4);
            }
        }

        // forget-gate GEMM: acc = h_c · Wf^T + bf
        f32x4 acc[2][2];
#pragma unroll
        for (int m = 0; m < 2; ++m)
#pragma unroll
            for (int n = 0; n < 2; ++n)
                acc[m][n] = (f32x4){bfr[n], bfr[n], bfr[n], bfr[n]};

        const unsigned char* bufc = &Abuf[c & 1][0];
#pragma unroll
        for (int k = 0; k < 8; ++k) {
            const int cb = colbase ^ (k << 6);
            bf16x8 a0 = *(const bf16x8*)(bufc + rb0 + cb);
            bf16x8 a1 = *(const bf16x8*)(bufc + rb1 + cb);
            acc[0][0] = __builtin_amdgcn_mfma_f32_16x16x32_bf16(a0, wfr[0][k], acc[0][0], 0, 0, 0);
            acc[0][1] = __builtin_amdgcn_mfma_f32_16x16x32_bf16(a0, wfr[1][k], acc[0][1], 0, 0, 0);
            acc[1][0] = __builtin_amdgcn_mfma_f32_16x16x32_bf16(a1, wfr[0][k], acc[1][0], 0, 0, 0);
            acc[1][1] = __builtin_amdgcn_mfma_f32_16x16x32_bf16(a1, wfr[1][k], acc[1][1], 0, 0, 0);
        }

        // stage next child into the other buffer; accumulate hidden_sum
        if (more) {
            unsigned char* bufn = &Abuf[(c & 1) ^ 1][0];
#pragma unroll
            for (int g = 0; g < 2; ++g) {
#pragma unroll
                for (int j = 0; j < 4; ++j) { hs[g][j] += hv[g][0][j]; hs[g][4 + j] += hv[g][1][j]; }
                *(bf16x8*)(bufn + sloff[g]) = pack8(hv[g][0], hv[g][1]);
            }
        }

        // node_memory += sigmoid(fg) * cm
#pragma unroll
        for (int m = 0; m < 2; ++m)
#pragma unroll
            for (int n = 0; n < 2; ++n)
#pragma unroll
                for (int j = 0; j < 4; ++j)
                    nmv[m][n][j] += sigm(acc[m][n][j]) * cmv[m][n][j];

        __syncthreads();
    }

    // ---- epilogue: hidden_sum -> LDS, then iou GEMM in 3 column chunks
#pragma unroll
    for (int g = 0; g < 2; ++g) {
        f32x4 a, b;
#pragma unroll
        for (int j = 0; j < 4; ++j) { a[j] = hs[g][j]; b[j] = hs[g][4 + j]; }
        *(bf16x8*)&Abuf[0][sloff[g]] = pack8(a, b);
    }
    __syncthreads();

    f32x4 gacc[3][2][2];   // q=0: input, 1: output, 2: memory(u)
#pragma unroll
    for (int q = 0; q < 3; ++q) {
        bf16x8 wq[2][8];
#pragma unroll
        for (int n = 0; n < 2; ++n) {
            const float* wrow = Wiou + (size_t)(q * 256 + wc0 + n * 16 + l15) * DD + l4 * 8;
#pragma unroll
            for (int k = 0; k < 8; ++k) {
                f32x4 x0 = *(const f32x4*)(wrow + k * 32);
                f32x4 x1 = *(const f32x4*)(wrow + k * 32 + 4);
                wq[n][k] = pack8(x0, x1);
            }
        }
        float bq[2];
#pragma unroll
        for (int n = 0; n < 2; ++n) bq[n] = biou[q * 256 + wc0 + n * 16 + l15];
#pragma unroll
        for (int m = 0; m < 2; ++m)
#pragma unroll
            for (int n = 0; n < 2; ++n)
                gacc[q][m][n] = (f32x4){bq[n], bq[n], bq[n], bq[n]};

        const unsigned char* bufc = &Abuf[0][0];
#pragma unroll
        for (int k = 0; k < 8; ++k) {
            const int cb = colbase ^ (k << 6);
            bf16x8 a0 = *(const bf16x8*)(bufc + rb0 + cb);
            bf16x8 a1 = *(const bf16x8*)(bufc + rb1 + cb);
            gacc[q][0][0] = __builtin_amdgcn_mfma_f32_16x16x32_bf16(a0, wq[0][k], gacc[q][0][0], 0, 0, 0);
            gacc[q][0][1] = __builtin_amdgcn_mfma_f32_16x16x32_bf16(a0, wq[1][k], gacc[q][0][1], 0, 0, 0);
            gacc[q][1][0] = __builtin_amdgcn_mfma_f32_16x16x32_bf16(a1, wq[0][k], gacc[q][1][0], 0, 0, 0);
            gacc[q][1][1] = __builtin_amdgcn_mfma_f32_16x16x32_bf16(a1, wq[1][k], gacc[q][1][1], 0, 0, 0);
        }
    }

    // ---- gates + final stores
#pragma unroll
    for (int m = 0; m < 2; ++m)
#pragma unroll
        for (int n = 0; n < 2; ++n)
#pragma unroll
            for (int j = 0; j < 4; ++j) {
                float ig = sigm(gacc[0][m][n][j]);
                float og = sigm(gacc[1][m][n][j]);
                float ug = tanhf_(gacc[2][m][n][j]);
                float mm = nmv[m][n][j] + ig * ug;
                float hh = og * tanhf_(mm);
                int row = b0 + m * 16 + l4 * 4 + j;
                int col = wc0 + n * 16 + l15;
                out[(size_t)row * DD + col] = mm;
                out[(size_t)(BB * DD) + (size_t)row * DD + col] = hh;
            }
}

extern "C" void kernel_launch(void* const* d_in, const int* in_sizes, int n_in,
                              void* d_out, int out_size, void* d_ws, size_t ws_size,
                              hipStream_t stream) {
    const float* cmem = (const float*)d_in[0];  // children_memory [16][16384][256]
    const float* chid = (const float*)d_in[1];  // children_hidden [16][16384][256]
    const float* Wf   = (const float*)d_in[2];  // [256][256]
    const float* bf   = (const float*)d_in[3];  // [256]
    const float* Wiou = (const float*)d_in[4];  // [768][256]
    const float* biou = (const float*)d_in[5];  // [768]
    float* out = (float*)d_out;                 // [2][16384][256]

    treelstm<<<BB / BT, NT, 0, stream>>>(cmem, chid, Wf, bf, Wiou, biou, out);
}